// Round 1
// baseline (473.258 us; speedup 1.0000x reference)
//
#include <hip/hip_runtime.h>
#include <hip/hip_bf16.h>

// LoRALinear with NF4 base: out = x @ W^T + (alpha/rank) * (x@A^T)@B^T
//  Fold: W_eff[o][i] = NF4[codes[o][i]] * scales[o][i/64] + 2 * sum_r B[o][r]*A[r][i]
//  Then one bf16 GEMM: out[M=8192][N=4096] = xb[M][K=4096] . W_eff[N][K]^T

#define IN_DIM  4096
#define OUT_DIM 4096
#define RANK    16
#define M_TOK   8192          // 4*2048
#define LORA_SCALE 2.0f       // ALPHA / RANK = 32/16

typedef __bf16 bf16_t;
typedef bf16_t bf16x8 __attribute__((ext_vector_type(8)));
typedef float  f32x4  __attribute__((ext_vector_type(4)));

__device__ __constant__ float NF4_TAB[16] = {
    -1.0f, -0.6961928009986877f, -0.5250730514526367f, -0.39491748809814453f,
    -0.28444138169288635f, -0.18477343022823334f, -0.09105003625154495f, 0.0f,
    0.07958029955625534f, 0.16093020141124725f, 0.24611230194568634f,
    0.33791524171829224f, 0.44070982933044434f, 0.5626170039176941f,
    0.7229568362236328f, 1.0f};

// ---------------------------------------------------------------- prep W_eff
__global__ __launch_bounds__(256) void prep_w(
    const int* __restrict__ codes,     // [O][I] int32 0..15
    const float* __restrict__ scales,  // [O][I/64]
    const float* __restrict__ la,      // [R][I]
    const float* __restrict__ lb,      // [O][R]
    bf16_t* __restrict__ W)            // [O][I] bf16 out
{
    __shared__ float nf4s[16];
    __shared__ float lbs[16];
    const int o = blockIdx.x;
    const int tid = threadIdx.x;
    if (tid < 16) {
        nf4s[tid] = NF4_TAB[tid];
        lbs[tid]  = lb[o * RANK + tid] * LORA_SCALE;
    }
    __syncthreads();

    #pragma unroll
    for (int it = 0; it < 2; ++it) {
        const int i0 = (it * 256 + tid) * 8;   // 8 consecutive elems, 64-block safe
        const size_t base = (size_t)o * IN_DIM + i0;
        int4 c0 = *(const int4*)(codes + base);
        int4 c1 = *(const int4*)(codes + base + 4);
        const float sc = scales[o * (IN_DIM / 64) + (i0 >> 6)];
        float w[8];
        w[0] = nf4s[c0.x] * sc; w[1] = nf4s[c0.y] * sc;
        w[2] = nf4s[c0.z] * sc; w[3] = nf4s[c0.w] * sc;
        w[4] = nf4s[c1.x] * sc; w[5] = nf4s[c1.y] * sc;
        w[6] = nf4s[c1.z] * sc; w[7] = nf4s[c1.w] * sc;
        #pragma unroll
        for (int r = 0; r < RANK; ++r) {
            const float b = lbs[r];
            float4 a0 = *(const float4*)(la + r * IN_DIM + i0);
            float4 a1 = *(const float4*)(la + r * IN_DIM + i0 + 4);
            w[0] += b * a0.x; w[1] += b * a0.y; w[2] += b * a0.z; w[3] += b * a0.w;
            w[4] += b * a1.x; w[5] += b * a1.y; w[6] += b * a1.z; w[7] += b * a1.w;
        }
        bf16x8 v;
        #pragma unroll
        for (int j = 0; j < 8; ++j) v[j] = (bf16_t)w[j];
        *(bf16x8*)(W + base) = v;
    }
}

// ---------------------------------------------------------------- cast x
__global__ __launch_bounds__(256) void cast_x(
    const float* __restrict__ x, bf16_t* __restrict__ y, int n8)
{
    const int stride = gridDim.x * blockDim.x;
    for (int i = blockIdx.x * blockDim.x + threadIdx.x; i < n8; i += stride) {
        const size_t e = (size_t)i * 8;
        float4 a = *(const float4*)(x + e);
        float4 b = *(const float4*)(x + e + 4);
        bf16x8 v;
        v[0] = (bf16_t)a.x; v[1] = (bf16_t)a.y; v[2] = (bf16_t)a.z; v[3] = (bf16_t)a.w;
        v[4] = (bf16_t)b.x; v[5] = (bf16_t)b.y; v[6] = (bf16_t)b.z; v[7] = (bf16_t)b.w;
        *(bf16x8*)(y + e) = v;
    }
}

// ---------------------------------------------------------------- GEMM (m97 structure)
// C[M][N] = A[M][K] . B[N][K]^T, bf16 in / f32 out.  128x128 tile, BK=32,
// 4 waves (2x2), each wave 64x64 via 4x4 frags of mfma_f32_16x16x32_bf16.
#define BM 128
#define BN 128
#define BK 32

__global__ __launch_bounds__(256) void gemm_bt(
    const bf16_t* __restrict__ A, const bf16_t* __restrict__ B,
    float* __restrict__ C, int M, int N, int K)
{
    __shared__ bf16_t sA[BM * BK];   // row-major [128][32], 64B rows
    __shared__ bf16_t sB[BN * BK];

    const int tid  = threadIdx.x;
    const int wave = tid >> 6;
    const int lane = tid & 63;
    const int m0 = blockIdx.y * BM;
    const int n0 = blockIdx.x * BN;
    const int wr = wave >> 1;        // wave row (0..1)
    const int wc = wave & 1;         // wave col (0..1)

    f32x4 acc[4][4];
    #pragma unroll
    for (int i = 0; i < 4; ++i)
        #pragma unroll
        for (int j = 0; j < 4; ++j) acc[i][j] = (f32x4)0.0f;

    const int frow = lane & 15;             // fragment row within 16
    const int fkb  = (lane >> 4) * 16;      // byte offset in 64B (=BK*2) row
    const size_t KB = (size_t)K * 2;        // global row bytes

    // staging decomposition: per wave q=0..1, tile byte off = wave*1024 + q*4096 + lane*16
    const int soff0 = wave * 1024 + lane * 16;

    for (int k0 = 0; k0 < K; k0 += BK) {
        #pragma unroll
        for (int q = 0; q < 2; ++q) {
            const int off  = soff0 + q * 4096;
            const int row  = off >> 6;       // /64B per row
            const int colb = off & 63;
            const char* gA = (const char*)A + (size_t)(m0 + row) * KB + (size_t)k0 * 2 + colb;
            const char* gB = (const char*)B + (size_t)(n0 + row) * KB + (size_t)k0 * 2 + colb;
            char* lA = (char*)sA + wave * 1024 + q * 4096;   // wave-uniform base
            char* lB = (char*)sB + wave * 1024 + q * 4096;
            __builtin_amdgcn_global_load_lds(
                (const __attribute__((address_space(1))) void*)gA,
                (__attribute__((address_space(3))) void*)lA, 16, 0, 0);
            __builtin_amdgcn_global_load_lds(
                (const __attribute__((address_space(1))) void*)gB,
                (__attribute__((address_space(3))) void*)lB, 16, 0, 0);
        }
        __syncthreads();

        bf16x8 af[4], bfr[4];
        #pragma unroll
        for (int f = 0; f < 4; ++f) {
            const int ra = wr * 64 + f * 16 + frow;
            af[f]  = *(const bf16x8*)((const char*)sA + ra * 64 + fkb);
            const int rb = wc * 64 + f * 16 + frow;
            bfr[f] = *(const bf16x8*)((const char*)sB + rb * 64 + fkb);
        }
        #pragma unroll
        for (int i = 0; i < 4; ++i)
            #pragma unroll
            for (int j = 0; j < 4; ++j)
                acc[i][j] = __builtin_amdgcn_mfma_f32_16x16x32_bf16(
                    af[i], bfr[j], acc[i][j], 0, 0, 0);
        __syncthreads();
    }

    // epilogue: D layout col=lane&15, row=(lane>>4)*4+reg  [m89-verified]
    const int crow = (lane >> 4) * 4;
    const int ccol = lane & 15;
    #pragma unroll
    for (int i = 0; i < 4; ++i) {
        #pragma unroll
        for (int j = 0; j < 4; ++j) {
            const int mb = m0 + wr * 64 + i * 16 + crow;
            const int nb = n0 + wc * 64 + j * 16 + ccol;
            #pragma unroll
            for (int r = 0; r < 4; ++r)
                C[(size_t)(mb + r) * N + nb] = acc[i][j][r];
        }
    }
}

// ---------------------------------------------------------------- launch
extern "C" void kernel_launch(void* const* d_in, const int* in_sizes, int n_in,
                              void* d_out, int out_size, void* d_ws, size_t ws_size,
                              hipStream_t stream) {
    const float* x      = (const float*)d_in[0];   // [4,2048,4096]
    const int*   codes  = (const int*)d_in[1];     // [4096,4096]
    const float* scales = (const float*)d_in[2];   // [4096,64]
    const float* la     = (const float*)d_in[3];   // [16,4096]
    const float* lb     = (const float*)d_in[4];   // [4096,16]
    float* out = (float*)d_out;

    // workspace: [0,32MiB) W_eff bf16 ; [32MiB,96MiB) x bf16
    bf16_t* W  = (bf16_t*)d_ws;
    bf16_t* xb = (bf16_t*)((char*)d_ws + (size_t)OUT_DIM * IN_DIM * 2);

    prep_w<<<OUT_DIM, 256, 0, stream>>>(codes, scales, la, lb, W);
    cast_x<<<2048, 256, 0, stream>>>(x, xb, (M_TOK * IN_DIM) / 8);

    dim3 grid(OUT_DIM / BN, M_TOK / BM);   // (32, 64)
    gemm_bt<<<grid, 256, 0, stream>>>(xb, W, out, M_TOK, OUT_DIM, IN_DIM);
}

// Round 2
// 473.065 us; speedup vs baseline: 1.0004x; 1.0004x over previous
//
#include <hip/hip_runtime.h>
#include <hip/hip_bf16.h>

// LoRALinear with NF4 base: out = x @ W^T + (alpha/rank) * (x@A^T)@B^T
//  Fold: W_eff[o][i] = NF4[codes[o][i]] * scales[o][i/64] + 2 * sum_r B[o][r]*A[r][i]
//  Then one bf16 GEMM: out[M=8192][N=4096] = xb[M][K=4096] . W_eff[N][K]^T

#define IN_DIM  4096
#define OUT_DIM 4096
#define RANK    16
#define M_TOK   8192          // 4*2048
#define LORA_SCALE 2.0f       // ALPHA / RANK = 32/16

typedef __bf16 bf16_t;
typedef bf16_t bf16x8 __attribute__((ext_vector_type(8)));
typedef float  f32x4  __attribute__((ext_vector_type(4)));

__device__ __constant__ float NF4_TAB[16] = {
    -1.0f, -0.6961928009986877f, -0.5250730514526367f, -0.39491748809814453f,
    -0.28444138169288635f, -0.18477343022823334f, -0.09105003625154495f, 0.0f,
    0.07958029955625534f, 0.16093020141124725f, 0.24611230194568634f,
    0.33791524171829224f, 0.44070982933044434f, 0.5626170039176941f,
    0.7229568362236328f, 1.0f};

// ---------------------------------------------------------------- prep W_eff
__global__ __launch_bounds__(256) void prep_w(
    const int* __restrict__ codes,     // [O][I] int32 0..15
    const float* __restrict__ scales,  // [O][I/64]
    const float* __restrict__ la,      // [R][I]
    const float* __restrict__ lb,      // [O][R]
    bf16_t* __restrict__ W)            // [O][I] bf16 out
{
    __shared__ float nf4s[16];
    __shared__ float lbs[16];
    const int o = blockIdx.x;
    const int tid = threadIdx.x;
    if (tid < 16) {
        nf4s[tid] = NF4_TAB[tid];
        lbs[tid]  = lb[o * RANK + tid] * LORA_SCALE;
    }
    __syncthreads();

    #pragma unroll
    for (int it = 0; it < 2; ++it) {
        const int i0 = (it * 256 + tid) * 8;   // 8 consecutive elems, 64-block safe
        const size_t base = (size_t)o * IN_DIM + i0;
        int4 c0 = *(const int4*)(codes + base);
        int4 c1 = *(const int4*)(codes + base + 4);
        const float sc = scales[o * (IN_DIM / 64) + (i0 >> 6)];
        float w[8];
        w[0] = nf4s[c0.x] * sc; w[1] = nf4s[c0.y] * sc;
        w[2] = nf4s[c0.z] * sc; w[3] = nf4s[c0.w] * sc;
        w[4] = nf4s[c1.x] * sc; w[5] = nf4s[c1.y] * sc;
        w[6] = nf4s[c1.z] * sc; w[7] = nf4s[c1.w] * sc;
        #pragma unroll
        for (int r = 0; r < RANK; ++r) {
            const float b = lbs[r];
            float4 a0 = *(const float4*)(la + r * IN_DIM + i0);
            float4 a1 = *(const float4*)(la + r * IN_DIM + i0 + 4);
            w[0] += b * a0.x; w[1] += b * a0.y; w[2] += b * a0.z; w[3] += b * a0.w;
            w[4] += b * a1.x; w[5] += b * a1.y; w[6] += b * a1.z; w[7] += b * a1.w;
        }
        bf16x8 v;
        #pragma unroll
        for (int j = 0; j < 8; ++j) v[j] = (bf16_t)w[j];
        *(bf16x8*)(W + base) = v;
    }
}

// ---------------------------------------------------------------- cast x
__global__ __launch_bounds__(256) void cast_x(
    const float* __restrict__ x, bf16_t* __restrict__ y, int n8)
{
    const int stride = gridDim.x * blockDim.x;
    for (int i = blockIdx.x * blockDim.x + threadIdx.x; i < n8; i += stride) {
        const size_t e = (size_t)i * 8;
        float4 a = *(const float4*)(x + e);
        float4 b = *(const float4*)(x + e + 4);
        bf16x8 v;
        v[0] = (bf16_t)a.x; v[1] = (bf16_t)a.y; v[2] = (bf16_t)a.z; v[3] = (bf16_t)a.w;
        v[4] = (bf16_t)b.x; v[5] = (bf16_t)b.y; v[6] = (bf16_t)b.z; v[7] = (bf16_t)b.w;
        *(bf16x8*)(y + e) = v;
    }
}

// ---------------------------------------------------------------- GEMM (m97 structure + chunk swizzle)
// C[M][N] = A[M][K] . B[N][K]^T, bf16 in / f32 out.  128x128 tile, BK=32,
// 4 waves (2x2), each wave 64x64 via 4x4 frags of mfma_f32_16x16x32_bf16.
//
// LDS rows are 64B (BK=32 bf16). Linear layout gives 8-way bank conflicts on
// the stride-64B ds_read_b128 (banks (row*16+c)%32 -> 2 banks per 16 lanes).
// Fix (rule 21: both-sides-or-neither with global_load_lds): LDS dest stays
// linear; the 16B chunk WITHIN each row is permuted on the global-source side
// by chunk ^= (row>>1)&3, and the ds_read applies the same XOR. Bank windows
// become {0,16,4,20,8,24,12,28}*2 per 16 lanes -> every bank exactly 2x = free.
#define BM 128
#define BN 128
#define BK 32

__global__ __launch_bounds__(256) void gemm_bt(
    const bf16_t* __restrict__ A, const bf16_t* __restrict__ B,
    float* __restrict__ C, int M, int N, int K)
{
    __shared__ bf16_t sA[BM * BK];   // row-major [128][32], 64B rows
    __shared__ bf16_t sB[BN * BK];

    const int tid  = threadIdx.x;
    const int wave = tid >> 6;
    const int lane = tid & 63;
    const int m0 = blockIdx.y * BM;
    const int n0 = blockIdx.x * BN;
    const int wr = wave >> 1;        // wave row (0..1)
    const int wc = wave & 1;         // wave col (0..1)

    f32x4 acc[4][4];
    #pragma unroll
    for (int i = 0; i < 4; ++i)
        #pragma unroll
        for (int j = 0; j < 4; ++j) acc[i][j] = (f32x4)0.0f;

    const int frow = lane & 15;             // fragment row within 16
    const int fkb  = (lane >> 4) * 16;      // logical chunk byte in 64B row
    const size_t KB = (size_t)K * 2;        // global row bytes

    // staging decomposition: per wave q=0..1, tile byte off = wave*1024 + q*4096 + lane*16
    const int soff0 = wave * 1024 + lane * 16;

    for (int k0 = 0; k0 < K; k0 += BK) {
        #pragma unroll
        for (int q = 0; q < 2; ++q) {
            const int off  = soff0 + q * 4096;
            const int row  = off >> 6;               // LDS row (64B each)
            const int chnk = (off >> 4) & 3;         // linear 16B chunk in row
            const int colb = (chnk ^ ((row >> 1) & 3)) << 4;  // pre-swizzled global chunk
            const char* gA = (const char*)A + (size_t)(m0 + row) * KB + (size_t)k0 * 2 + colb;
            const char* gB = (const char*)B + (size_t)(n0 + row) * KB + (size_t)k0 * 2 + colb;
            char* lA = (char*)sA + wave * 1024 + q * 4096;   // wave-uniform base (linear dest)
            char* lB = (char*)sB + wave * 1024 + q * 4096;
            __builtin_amdgcn_global_load_lds(
                (const __attribute__((address_space(1))) void*)gA,
                (__attribute__((address_space(3))) void*)lA, 16, 0, 0);
            __builtin_amdgcn_global_load_lds(
                (const __attribute__((address_space(1))) void*)gB,
                (__attribute__((address_space(3))) void*)lB, 16, 0, 0);
        }
        __syncthreads();

        bf16x8 af[4], bfr[4];
        #pragma unroll
        for (int f = 0; f < 4; ++f) {
            const int ra = wr * 64 + f * 16 + frow;
            const int ca = fkb ^ (((ra >> 1) & 3) << 4);     // same XOR on read
            af[f]  = *(const bf16x8*)((const char*)sA + ra * 64 + ca);
            const int rb = wc * 64 + f * 16 + frow;
            const int cb = fkb ^ (((rb >> 1) & 3) << 4);
            bfr[f] = *(const bf16x8*)((const char*)sB + rb * 64 + cb);
        }
        #pragma unroll
        for (int i = 0; i < 4; ++i)
            #pragma unroll
            for (int j = 0; j < 4; ++j)
                acc[i][j] = __builtin_amdgcn_mfma_f32_16x16x32_bf16(
                    af[i], bfr[j], acc[i][j], 0, 0, 0);
        __syncthreads();
    }

    // epilogue: D layout col=lane&15, row=(lane>>4)*4+reg  [m89-verified]
    const int crow = (lane >> 4) * 4;
    const int ccol = lane & 15;
    #pragma unroll
    for (int i = 0; i < 4; ++i) {
        #pragma unroll
        for (int j = 0; j < 4; ++j) {
            const int mb = m0 + wr * 64 + i * 16 + crow;
            const int nb = n0 + wc * 64 + j * 16 + ccol;
            #pragma unroll
            for (int r = 0; r < 4; ++r)
                C[(size_t)(mb + r) * N + nb] = acc[i][j][r];
        }
    }
}

// ---------------------------------------------------------------- launch
extern "C" void kernel_launch(void* const* d_in, const int* in_sizes, int n_in,
                              void* d_out, int out_size, void* d_ws, size_t ws_size,
                              hipStream_t stream) {
    const float* x      = (const float*)d_in[0];   // [4,2048,4096]
    const int*   codes  = (const int*)d_in[1];     // [4096,4096]
    const float* scales = (const float*)d_in[2];   // [4096,64]
    const float* la     = (const float*)d_in[3];   // [16,4096]
    const float* lb     = (const float*)d_in[4];   // [4096,16]
    float* out = (float*)d_out;

    // workspace: [0,32MiB) W_eff bf16 ; [32MiB,96MiB) x bf16
    bf16_t* W  = (bf16_t*)d_ws;
    bf16_t* xb = (bf16_t*)((char*)d_ws + (size_t)OUT_DIM * IN_DIM * 2);

    prep_w<<<OUT_DIM, 256, 0, stream>>>(codes, scales, la, lb, W);
    cast_x<<<2048, 256, 0, stream>>>(x, xb, (M_TOK * IN_DIM) / 8);

    dim3 grid(OUT_DIM / BN, M_TOK / BM);   // (32, 64)
    gemm_bt<<<grid, 256, 0, stream>>>(xb, W, out, M_TOK, OUT_DIM, IN_DIM);
}

// Round 3
// 351.411 us; speedup vs baseline: 1.3467x; 1.3462x over previous
//
#include <hip/hip_runtime.h>
#include <hip/hip_bf16.h>

// LoRALinear with NF4 base: out = x @ W^T + (alpha/rank) * (x@A^T)@B^T
//  Fold: W_eff[o][i] = NF4[codes[o][i]] * scales[o][i/64] + 2 * sum_r B[o][r]*A[r][i]
//  Then one bf16 GEMM: out[M=8192][N=4096] = xb[M][K=4096] . W_eff[N][K]^T
//
// GEMM structure (this round): 256x256 tile, BK=32, TRI-buffered LDS with
// counted vmcnt(8) (never 0 in main loop) + raw s_barrier (no implicit
// vmcnt(0) drain) -> stage latency of tile t hidden under steps t..t+1.

#define IN_DIM  4096
#define OUT_DIM 4096
#define RANK    16
#define M_TOK   8192          // 4*2048
#define LORA_SCALE 2.0f       // ALPHA / RANK = 32/16

typedef __bf16 bf16_t;
typedef bf16_t bf16x8 __attribute__((ext_vector_type(8)));
typedef float  f32x4  __attribute__((ext_vector_type(4)));

__device__ __constant__ float NF4_TAB[16] = {
    -1.0f, -0.6961928009986877f, -0.5250730514526367f, -0.39491748809814453f,
    -0.28444138169288635f, -0.18477343022823334f, -0.09105003625154495f, 0.0f,
    0.07958029955625534f, 0.16093020141124725f, 0.24611230194568634f,
    0.33791524171829224f, 0.44070982933044434f, 0.5626170039176941f,
    0.7229568362236328f, 1.0f};

// ---------------------------------------------------------------- prep W_eff
__global__ __launch_bounds__(256) void prep_w(
    const int* __restrict__ codes,     // [O][I] int32 0..15
    const float* __restrict__ scales,  // [O][I/64]
    const float* __restrict__ la,      // [R][I]
    const float* __restrict__ lb,      // [O][R]
    bf16_t* __restrict__ W)            // [O][I] bf16 out
{
    __shared__ float nf4s[16];
    __shared__ float lbs[16];
    const int o = blockIdx.x;
    const int tid = threadIdx.x;
    if (tid < 16) {
        nf4s[tid] = NF4_TAB[tid];
        lbs[tid]  = lb[o * RANK + tid] * LORA_SCALE;
    }
    __syncthreads();

    #pragma unroll
    for (int it = 0; it < 2; ++it) {
        const int i0 = (it * 256 + tid) * 8;   // 8 consecutive elems, 64-block safe
        const size_t base = (size_t)o * IN_DIM + i0;
        int4 c0 = *(const int4*)(codes + base);
        int4 c1 = *(const int4*)(codes + base + 4);
        const float sc = scales[o * (IN_DIM / 64) + (i0 >> 6)];
        float w[8];
        w[0] = nf4s[c0.x] * sc; w[1] = nf4s[c0.y] * sc;
        w[2] = nf4s[c0.z] * sc; w[3] = nf4s[c0.w] * sc;
        w[4] = nf4s[c1.x] * sc; w[5] = nf4s[c1.y] * sc;
        w[6] = nf4s[c1.z] * sc; w[7] = nf4s[c1.w] * sc;
        #pragma unroll
        for (int r = 0; r < RANK; ++r) {
            const float b = lbs[r];
            float4 a0 = *(const float4*)(la + r * IN_DIM + i0);
            float4 a1 = *(const float4*)(la + r * IN_DIM + i0 + 4);
            w[0] += b * a0.x; w[1] += b * a0.y; w[2] += b * a0.z; w[3] += b * a0.w;
            w[4] += b * a1.x; w[5] += b * a1.y; w[6] += b * a1.z; w[7] += b * a1.w;
        }
        bf16x8 v;
        #pragma unroll
        for (int j = 0; j < 8; ++j) v[j] = (bf16_t)w[j];
        *(bf16x8*)(W + base) = v;
    }
}

// ---------------------------------------------------------------- cast x
__global__ __launch_bounds__(256) void cast_x(
    const float* __restrict__ x, bf16_t* __restrict__ y, int n8)
{
    const int stride = gridDim.x * blockDim.x;
    for (int i = blockIdx.x * blockDim.x + threadIdx.x; i < n8; i += stride) {
        const size_t e = (size_t)i * 8;
        float4 a = *(const float4*)(x + e);
        float4 b = *(const float4*)(x + e + 4);
        bf16x8 v;
        v[0] = (bf16_t)a.x; v[1] = (bf16_t)a.y; v[2] = (bf16_t)a.z; v[3] = (bf16_t)a.w;
        v[4] = (bf16_t)b.x; v[5] = (bf16_t)b.y; v[6] = (bf16_t)b.z; v[7] = (bf16_t)b.w;
        *(bf16x8*)(y + e) = v;
    }
}

// ---------------------------------------------------------------- GEMM
// C[M][N] = A[M][K] . B[N][K]^T, bf16 in / f32 out.
// 256x256 tile, BK=32, 512 threads = 8 waves (2M x 4N), wave tile 128x64,
// 32 x mfma_f32_16x16x32_bf16 per wave per K-step.
// LDS: 3 buffers x (A 16KB + B 16KB) = 96 KB. Prefetch distance 2 tiles.
// Chunk swizzle (verified R1, conflicts=0): LDS[row][c] holds global chunk
// c ^ ((row>>1)&3); applied on the global-load source AND the ds_read addr.
#define BM 256
#define BN 256
#define BK 32
#define NT (IN_DIM / BK)     // 128 K-steps

__global__ __launch_bounds__(512, 2) void gemm_bt(
    const bf16_t* __restrict__ A, const bf16_t* __restrict__ B,
    float* __restrict__ C)
{
    __shared__ bf16_t lds[3][2][BM * BK];   // [buf][A=0/B=1][256*32], 96 KiB

    const int tid  = threadIdx.x;
    const int wave = tid >> 6;
    const int lane = tid & 63;

    // XCD-aware swizzle: nwg = 512, divisible by 8 -> simple bijection
    const int flat = blockIdx.y * gridDim.x + blockIdx.x;     // 0..511
    const int swz  = (flat & 7) * 64 + (flat >> 3);
    const int bx = swz & 15;          // N tile  (16)
    const int by = swz >> 4;          // M tile  (32)
    const int m0 = by * BM;
    const int n0 = bx * BN;

    const int wr = wave >> 2;         // 0..1  (M half)
    const int wc = wave & 3;          // 0..3  (N quarter)

    f32x4 acc[8][4];
    #pragma unroll
    for (int i = 0; i < 8; ++i)
        #pragma unroll
        for (int j = 0; j < 4; ++j) acc[i][j] = (f32x4)0.0f;

    const size_t KB = (size_t)IN_DIM * 2;     // global row bytes

    // ---- staging addressing (2 passes of 8KB per operand per tile)
    int s_row[2], s_gc[2];
    #pragma unroll
    for (int p = 0; p < 2; ++p) {
        const int off = p * 8192 + tid * 16;
        s_row[p] = off >> 6;                              // LDS row (64B rows)
        s_gc[p]  = ((off >> 4) & 3) ^ ((s_row[p] >> 1) & 3);  // pre-swizzled global chunk
    }
    const char* gA = (const char*)A;
    const char* gB = (const char*)B;

    // ---- fragment read offsets (byte offsets within a 16KB region)
    const int frow = lane & 15;
    const int fch  = lane >> 4;
    int offA[8], offB[4];
    #pragma unroll
    for (int i = 0; i < 8; ++i) {
        const int ra = wr * 128 + i * 16 + frow;
        offA[i] = ra * 64 + ((fch ^ ((ra >> 1) & 3)) << 4);
    }
    #pragma unroll
    for (int j = 0; j < 4; ++j) {
        const int rb = wc * 64 + j * 16 + frow;
        offB[j] = rb * 64 + ((fch ^ ((rb >> 1) & 3)) << 4);
    }

#define STAGE(tt, bidx) do {                                                   \
    const size_t kb_ = (size_t)(tt) * (BK * 2);                                \
    _Pragma("unroll")                                                          \
    for (int p = 0; p < 2; ++p) {                                              \
        const char* srcA = gA + (size_t)(m0 + s_row[p]) * KB + kb_ + (s_gc[p] << 4); \
        const char* srcB = gB + (size_t)(n0 + s_row[p]) * KB + kb_ + (s_gc[p] << 4); \
        char* dA = (char*)&lds[bidx][0][0] + p * 8192 + wave * 1024;           \
        char* dB = (char*)&lds[bidx][1][0] + p * 8192 + wave * 1024;           \
        __builtin_amdgcn_global_load_lds(                                      \
            (const __attribute__((address_space(1))) void*)srcA,               \
            (__attribute__((address_space(3))) void*)dA, 16, 0, 0);            \
        __builtin_amdgcn_global_load_lds(                                      \
            (const __attribute__((address_space(1))) void*)srcB,               \
            (__attribute__((address_space(3))) void*)dB, 16, 0, 0);            \
    }                                                                          \
} while (0)

    // COMPUTE: ds_read frags -> lgkmcnt(0) -> barrier#2 (releases overwrite
    // of this buffer) -> MFMA (overlaps next step's stage+reads)
#define COMPUTE(bidx) do {                                                     \
    const char* bA_ = (const char*)&lds[bidx][0][0];                           \
    const char* bB_ = (const char*)&lds[bidx][1][0];                           \
    bf16x8 af[8], bfr[4];                                                      \
    _Pragma("unroll")                                                          \
    for (int i = 0; i < 8; ++i) af[i] = *(const bf16x8*)(bA_ + offA[i]);       \
    _Pragma("unroll")                                                          \
    for (int j = 0; j < 4; ++j) bfr[j] = *(const bf16x8*)(bB_ + offB[j]);      \
    asm volatile("s_waitcnt lgkmcnt(0)" ::: "memory");                         \
    __builtin_amdgcn_s_barrier();                                              \
    __builtin_amdgcn_s_setprio(1);                                             \
    _Pragma("unroll")                                                          \
    for (int i = 0; i < 8; ++i)                                                \
        _Pragma("unroll")                                                      \
        for (int j = 0; j < 4; ++j)                                            \
            acc[i][j] = __builtin_amdgcn_mfma_f32_16x16x32_bf16(               \
                af[i], bfr[j], acc[i][j], 0, 0, 0);                            \
    __builtin_amdgcn_s_setprio(0);                                             \
} while (0)

    // ---- prologue: stage tiles 0,1
    STAGE(0, 0);
    STAGE(1, 1);

    // ---- main loop: compute t from buf t%3, stage t+2 into (t+2)%3
    int cb = 0, sb = 2;
    for (int t = 0; t < NT - 2; ++t) {
        STAGE(t + 2, sb);
        asm volatile("s_waitcnt vmcnt(8)" ::: "memory");   // tile t landed; 2 tiles in flight
        __builtin_amdgcn_s_barrier();                      // barrier#1
        COMPUTE(cb);
        cb = (cb == 2) ? 0 : cb + 1;
        sb = (sb == 2) ? 0 : sb + 1;
    }
    // ---- tail: t = NT-2 (cb=0 since 126%3==0), then t = NT-1
    asm volatile("s_waitcnt vmcnt(4)" ::: "memory");
    __builtin_amdgcn_s_barrier();
    COMPUTE(cb);
    cb = (cb == 2) ? 0 : cb + 1;
    asm volatile("s_waitcnt vmcnt(0)" ::: "memory");
    __builtin_amdgcn_s_barrier();
    COMPUTE(cb);

    // ---- epilogue: D layout col=lane&15, row=(lane>>4)*4+reg [m89-verified]
    const int crow = (lane >> 4) * 4;
    const int ccol = lane & 15;
    #pragma unroll
    for (int i = 0; i < 8; ++i) {
        #pragma unroll
        for (int j = 0; j < 4; ++j) {
            const int mb = m0 + wr * 128 + i * 16 + crow;
            const int nb = n0 + wc * 64 + j * 16 + ccol;
            #pragma unroll
            for (int r = 0; r < 4; ++r)
                C[(size_t)(mb + r) * OUT_DIM + nb] = acc[i][j][r];
        }
    }
#undef STAGE
#undef COMPUTE
}

// ---------------------------------------------------------------- launch
extern "C" void kernel_launch(void* const* d_in, const int* in_sizes, int n_in,
                              void* d_out, int out_size, void* d_ws, size_t ws_size,
                              hipStream_t stream) {
    const float* x      = (const float*)d_in[0];   // [4,2048,4096]
    const int*   codes  = (const int*)d_in[1];     // [4096,4096]
    const float* scales = (const float*)d_in[2];   // [4096,64]
    const float* la     = (const float*)d_in[3];   // [16,4096]
    const float* lb     = (const float*)d_in[4];   // [4096,16]
    float* out = (float*)d_out;

    // workspace: [0,32MiB) W_eff bf16 ; [32MiB,96MiB) x bf16
    bf16_t* W  = (bf16_t*)d_ws;
    bf16_t* xb = (bf16_t*)((char*)d_ws + (size_t)OUT_DIM * IN_DIM * 2);

    prep_w<<<OUT_DIM, 256, 0, stream>>>(codes, scales, la, lb, W);
    cast_x<<<2048, 256, 0, stream>>>(x, xb, (M_TOK * IN_DIM) / 8);

    dim3 grid(OUT_DIM / BN, M_TOK / BM);   // (16, 32) = 512 blocks
    gemm_bt<<<grid, 512, 0, stream>>>(xb, W, out);
}

// Round 4
// 288.063 us; speedup vs baseline: 1.6429x; 1.2199x over previous
//
#include <hip/hip_runtime.h>
#include <hip/hip_bf16.h>

// LoRALinear with NF4 base: out = x @ W^T + (alpha/rank) * (x@A^T)@B^T
//  Fold: W_eff[o][i] = NF4[codes[o][i]] * scales[o][i/64] + 2 * sum_r B[o][r]*A[r][i]
//  Then one bf16 GEMM: out[M=8192][N=4096] = xb[M][K=4096] . W_eff[N][K]^T
//
// GEMM (this round): 256x256 tile, BK=32, QUAD-buffered LDS (128KB), counted
// vmcnt(8), ONE barrier per K-step, and frag-read pipelining: ds_reads of
// tile t+1 (into the alternate E/O register set) overlap MFMA of tile t.

#define IN_DIM  4096
#define OUT_DIM 4096
#define RANK    16
#define M_TOK   8192          // 4*2048
#define LORA_SCALE 2.0f       // ALPHA / RANK = 32/16

typedef __bf16 bf16_t;
typedef bf16_t bf16x8 __attribute__((ext_vector_type(8)));
typedef float  f32x4  __attribute__((ext_vector_type(4)));

__device__ __constant__ float NF4_TAB[16] = {
    -1.0f, -0.6961928009986877f, -0.5250730514526367f, -0.39491748809814453f,
    -0.28444138169288635f, -0.18477343022823334f, -0.09105003625154495f, 0.0f,
    0.07958029955625534f, 0.16093020141124725f, 0.24611230194568634f,
    0.33791524171829224f, 0.44070982933044434f, 0.5626170039176941f,
    0.7229568362236328f, 1.0f};

// ---------------------------------------------------------------- prep W_eff
// 4 o-rows per thread: each la float4 load feeds 4 rows (la L2 traffic /4).
__global__ __launch_bounds__(256) void prep_w(
    const int* __restrict__ codes,     // [O][I] int32 0..15
    const float* __restrict__ scales,  // [O][I/64]
    const float* __restrict__ la,      // [R][I]
    const float* __restrict__ lb,      // [O][R]
    bf16_t* __restrict__ W)            // [O][I] bf16 out
{
    __shared__ float nf4s[16];
    __shared__ float lbs[4][16];
    const int o0 = blockIdx.x * 4;
    const int tid = threadIdx.x;
    if (tid < 64) lbs[tid >> 4][tid & 15] = lb[(o0 + (tid >> 4)) * RANK + (tid & 15)] * LORA_SCALE;
    else if (tid < 80) nf4s[tid - 64] = NF4_TAB[tid - 64];
    __syncthreads();

    #pragma unroll
    for (int it = 0; it < 2; ++it) {
        const int i0 = (it * 256 + tid) * 8;   // 8 consecutive elems, 64-block safe
        float w[4][8];
        #pragma unroll
        for (int oo = 0; oo < 4; ++oo) {
            const size_t base = (size_t)(o0 + oo) * IN_DIM + i0;
            int4 c0 = *(const int4*)(codes + base);
            int4 c1 = *(const int4*)(codes + base + 4);
            const float sc = scales[(o0 + oo) * (IN_DIM / 64) + (i0 >> 6)];
            w[oo][0] = nf4s[c0.x] * sc; w[oo][1] = nf4s[c0.y] * sc;
            w[oo][2] = nf4s[c0.z] * sc; w[oo][3] = nf4s[c0.w] * sc;
            w[oo][4] = nf4s[c1.x] * sc; w[oo][5] = nf4s[c1.y] * sc;
            w[oo][6] = nf4s[c1.z] * sc; w[oo][7] = nf4s[c1.w] * sc;
        }
        #pragma unroll
        for (int r = 0; r < RANK; ++r) {
            float4 a0 = *(const float4*)(la + r * IN_DIM + i0);
            float4 a1 = *(const float4*)(la + r * IN_DIM + i0 + 4);
            #pragma unroll
            for (int oo = 0; oo < 4; ++oo) {
                const float b = lbs[oo][r];
                w[oo][0] += b * a0.x; w[oo][1] += b * a0.y;
                w[oo][2] += b * a0.z; w[oo][3] += b * a0.w;
                w[oo][4] += b * a1.x; w[oo][5] += b * a1.y;
                w[oo][6] += b * a1.z; w[oo][7] += b * a1.w;
            }
        }
        #pragma unroll
        for (int oo = 0; oo < 4; ++oo) {
            bf16x8 v;
            #pragma unroll
            for (int j = 0; j < 8; ++j) v[j] = (bf16_t)w[oo][j];
            *(bf16x8*)(W + (size_t)(o0 + oo) * IN_DIM + i0) = v;
        }
    }
}

// ---------------------------------------------------------------- cast x
__global__ __launch_bounds__(256) void cast_x(
    const float* __restrict__ x, bf16_t* __restrict__ y, int n8)
{
    const int stride = gridDim.x * blockDim.x;
    for (int i = blockIdx.x * blockDim.x + threadIdx.x; i < n8; i += stride) {
        const size_t e = (size_t)i * 8;
        float4 a = *(const float4*)(x + e);
        float4 b = *(const float4*)(x + e + 4);
        bf16x8 v;
        v[0] = (bf16_t)a.x; v[1] = (bf16_t)a.y; v[2] = (bf16_t)a.z; v[3] = (bf16_t)a.w;
        v[4] = (bf16_t)b.x; v[5] = (bf16_t)b.y; v[6] = (bf16_t)b.z; v[7] = (bf16_t)b.w;
        *(bf16x8*)(y + e) = v;
    }
}

// ---------------------------------------------------------------- GEMM
// C[M][N] = A[M][K] . B[N][K]^T, bf16 in / f32 out.
// 256x256 tile, BK=32, 512 threads = 8 waves (2M x 4N), wave tile 128x64.
// Chunk swizzle (verified R1/R2, conflicts=0): LDS[row][c] holds global chunk
// c ^ ((row>>1)&3); applied on global-load source AND ds_read addr.
#define BM 256
#define BN 256
#define BK 32
#define NT (IN_DIM / BK)     // 128 K-steps

__global__ __launch_bounds__(512, 2) void gemm_bt(
    const bf16_t* __restrict__ A, const bf16_t* __restrict__ B,
    float* __restrict__ C)
{
    __shared__ bf16_t lds[4][2][BM * BK];   // [buf][A=0/B=1][256*32], 128 KiB

    const int tid  = threadIdx.x;
    const int wave = tid >> 6;
    const int lane = tid & 63;

    // XCD-aware swizzle: nwg = 512, divisible by 8 -> simple bijection
    const int flat = blockIdx.y * gridDim.x + blockIdx.x;     // 0..511
    const int swz  = (flat & 7) * 64 + (flat >> 3);
    const int bx = swz & 15;          // N tile  (16)
    const int by = swz >> 4;          // M tile  (32)
    const int m0 = by * BM;
    const int n0 = bx * BN;

    const int wr = wave >> 2;         // 0..1  (M half)
    const int wc = wave & 3;          // 0..3  (N quarter)

    f32x4 acc[8][4];
    #pragma unroll
    for (int i = 0; i < 8; ++i)
        #pragma unroll
        for (int j = 0; j < 4; ++j) acc[i][j] = (f32x4)0.0f;

    const size_t KB = (size_t)IN_DIM * 2;     // global row bytes

    // ---- staging addressing (2 passes of 8KB per operand per tile)
    int s_row[2], s_gc[2];
    #pragma unroll
    for (int p = 0; p < 2; ++p) {
        const int off = p * 8192 + tid * 16;
        s_row[p] = off >> 6;                              // LDS row (64B rows)
        s_gc[p]  = ((off >> 4) & 3) ^ ((s_row[p] >> 1) & 3);  // pre-swizzled global chunk
    }
    const char* gA = (const char*)A;
    const char* gB = (const char*)B;

    // ---- fragment read offsets (byte offsets within a 16KB region)
    const int frow = lane & 15;
    const int fch  = lane >> 4;
    int offA[8], offB[4];
    #pragma unroll
    for (int i = 0; i < 8; ++i) {
        const int ra = wr * 128 + i * 16 + frow;
        offA[i] = ra * 64 + ((fch ^ ((ra >> 1) & 3)) << 4);
    }
    #pragma unroll
    for (int j = 0; j < 4; ++j) {
        const int rb = wc * 64 + j * 16 + frow;
        offB[j] = rb * 64 + ((fch ^ ((rb >> 1) & 3)) << 4);
    }

#define LD(bidx) ((const char*)&lds[bidx][0][0])

#define STAGE(tt, bidx) do {                                                   \
    const size_t kb_ = (size_t)(tt) * (BK * 2);                                \
    _Pragma("unroll")                                                          \
    for (int p = 0; p < 2; ++p) {                                              \
        const char* srcA = gA + (size_t)(m0 + s_row[p]) * KB + kb_ + (s_gc[p] << 4); \
        const char* srcB = gB + (size_t)(n0 + s_row[p]) * KB + kb_ + (s_gc[p] << 4); \
        char* dA = (char*)&lds[bidx][0][0] + p * 8192 + wave * 1024;           \
        char* dB = (char*)&lds[bidx][1][0] + p * 8192 + wave * 1024;           \
        __builtin_amdgcn_global_load_lds(                                      \
            (const __attribute__((address_space(1))) void*)srcA,               \
            (__attribute__((address_space(3))) void*)dA, 16, 0, 0);            \
        __builtin_amdgcn_global_load_lds(                                      \
            (const __attribute__((address_space(1))) void*)srcB,               \
            (__attribute__((address_space(3))) void*)dB, 16, 0, 0);            \
    }                                                                          \
} while (0)

#define READ_FRAGS(AF, BF, base_) do {                                         \
    const char* bA_ = (base_);                                                 \
    const char* bB_ = (base_) + 16384;                                         \
    _Pragma("unroll")                                                          \
    for (int i = 0; i < 8; ++i) AF[i] = *(const bf16x8*)(bA_ + offA[i]);       \
    _Pragma("unroll")                                                          \
    for (int j = 0; j < 4; ++j) BF[j] = *(const bf16x8*)(bB_ + offB[j]);       \
} while (0)

// rule #18: sched_barrier(0) after lgkmcnt(0) so MFMA can't hoist above it
#define WAIT_LGKM do {                                                         \
    asm volatile("s_waitcnt lgkmcnt(0)" ::: "memory");                         \
    __builtin_amdgcn_sched_barrier(0);                                         \
} while (0)

#define MFMA_HALF(AF, BF, I0) do {                                             \
    __builtin_amdgcn_s_setprio(1);                                             \
    _Pragma("unroll")                                                          \
    for (int i = 0; i < 4; ++i)                                                \
        _Pragma("unroll")                                                      \
        for (int j = 0; j < 4; ++j)                                            \
            acc[(I0) + i][j] = __builtin_amdgcn_mfma_f32_16x16x32_bf16(        \
                AF[(I0) + i], BF[j], acc[(I0) + i][j], 0, 0, 0);               \
    __builtin_amdgcn_s_setprio(0);                                             \
} while (0)

    bf16x8 afE[8], bfE[4], afO[8], bfO[4];

    // ---- prologue: stage tiles 0,1,2; read frags(0) into E
    STAGE(0, 0);
    STAGE(1, 1);
    STAGE(2, 2);
    asm volatile("s_waitcnt vmcnt(8)" ::: "memory");   // tile 0 landed
    __builtin_amdgcn_s_barrier();
    READ_FRAGS(afE, bfE, LD(0));

    // ---- main loop: 2 tiles per iteration, alternating E/O frag sets
    for (int t = 0; t < NT - 4; t += 2) {              // t = 0,2,...,122
        // tile t (E)
        STAGE(t + 3, (t + 3) & 3);
        WAIT_LGKM;
        MFMA_HALF(afE, bfE, 0);
        asm volatile("s_waitcnt vmcnt(8)" ::: "memory");   // tile t+1 landed
        __builtin_amdgcn_s_barrier();
        READ_FRAGS(afO, bfO, LD((t + 1) & 3));
        MFMA_HALF(afE, bfE, 4);
        // tile t+1 (O)
        STAGE(t + 4, (t + 4) & 3);
        WAIT_LGKM;
        MFMA_HALF(afO, bfO, 0);
        asm volatile("s_waitcnt vmcnt(8)" ::: "memory");   // tile t+2 landed
        __builtin_amdgcn_s_barrier();
        READ_FRAGS(afE, bfE, LD((t + 2) & 3));
        MFMA_HALF(afO, bfO, 4);
    }

    // ---- tail: tiles 124(E),125(O),126(E),127(O); stage 127 first
    STAGE(127, 3);
    WAIT_LGKM;
    MFMA_HALF(afE, bfE, 0);
    asm volatile("s_waitcnt vmcnt(8)" ::: "memory");       // tile 125 landed
    __builtin_amdgcn_s_barrier();
    READ_FRAGS(afO, bfO, LD(1));
    MFMA_HALF(afE, bfE, 4);

    WAIT_LGKM;
    MFMA_HALF(afO, bfO, 0);
    asm volatile("s_waitcnt vmcnt(4)" ::: "memory");       // tile 126 landed
    __builtin_amdgcn_s_barrier();
    READ_FRAGS(afE, bfE, LD(2));
    MFMA_HALF(afO, bfO, 4);

    WAIT_LGKM;
    MFMA_HALF(afE, bfE, 0);
    asm volatile("s_waitcnt vmcnt(0)" ::: "memory");       // tile 127 landed
    __builtin_amdgcn_s_barrier();
    READ_FRAGS(afO, bfO, LD(3));
    MFMA_HALF(afE, bfE, 4);

    WAIT_LGKM;
    MFMA_HALF(afO, bfO, 0);
    MFMA_HALF(afO, bfO, 4);

    // ---- epilogue: D layout col=lane&15, row=(lane>>4)*4+reg [m89-verified]
    const int crow = (lane >> 4) * 4;
    const int ccol = lane & 15;
    #pragma unroll
    for (int i = 0; i < 8; ++i) {
        #pragma unroll
        for (int j = 0; j < 4; ++j) {
            const int mb = m0 + wr * 128 + i * 16 + crow;
            const int nb = n0 + wc * 64 + j * 16 + ccol;
            #pragma unroll
            for (int r = 0; r < 4; ++r)
                C[(size_t)(mb + r) * OUT_DIM + nb] = acc[i][j][r];
        }
    }
#undef STAGE
#undef READ_FRAGS
#undef WAIT_LGKM
#undef MFMA_HALF
#undef LD
}

// ---------------------------------------------------------------- launch
extern "C" void kernel_launch(void* const* d_in, const int* in_sizes, int n_in,
                              void* d_out, int out_size, void* d_ws, size_t ws_size,
                              hipStream_t stream) {
    const float* x      = (const float*)d_in[0];   // [4,2048,4096]
    const int*   codes  = (const int*)d_in[1];     // [4096,4096]
    const float* scales = (const float*)d_in[2];   // [4096,64]
    const float* la     = (const float*)d_in[3];   // [16,4096]
    const float* lb     = (const float*)d_in[4];   // [4096,16]
    float* out = (float*)d_out;

    // workspace: [0,32MiB) W_eff bf16 ; [32MiB,96MiB) x bf16
    bf16_t* W  = (bf16_t*)d_ws;
    bf16_t* xb = (bf16_t*)((char*)d_ws + (size_t)OUT_DIM * IN_DIM * 2);

    prep_w<<<OUT_DIM / 4, 256, 0, stream>>>(codes, scales, la, lb, W);
    cast_x<<<2048, 256, 0, stream>>>(x, xb, (M_TOK * IN_DIM) / 8);

    dim3 grid(OUT_DIM / BN, M_TOK / BM);   // (16, 32) = 512 blocks
    gemm_bt<<<grid, 512, 0, stream>>>(xb, W, out);
}